// Round 3
// baseline (375.538 us; speedup 1.0000x reference)
//
#include <hip/hip_runtime.h>
#include <stdint.h>

#define BB 16
#define LC 2048
#define LQ 1024
#define DD 512

typedef _Float16 f16x8 __attribute__((ext_vector_type(8)));
typedef _Float16 f16x4 __attribute__((ext_vector_type(4)));
typedef float f32x4 __attribute__((ext_vector_type(4)));

#define MFMA16 __builtin_amdgcn_mfma_f32_16x16x32_f16

// Async global->LDS, 16B per lane. LDS dest = wave-uniform base + lane*16.
__device__ __forceinline__ void async16(_Float16* lds, const _Float16* g) {
    __builtin_amdgcn_global_load_lds(
        (const __attribute__((address_space(1))) void*)g,
        (__attribute__((address_space(3))) void*)lds, 16, 0, 0);
}

// Per 64x64 tile of context: write cm = ctx*wm (i,d)-major fp16,
// ct = ctx^T (d,i)-major fp16 (via LDS transpose), and accumulate cb = ctx.wc
__global__ __launch_bounds__(256) void prep_ctx(
    const float* __restrict__ ctx, const float* __restrict__ w,
    _Float16* __restrict__ cm, _Float16* __restrict__ ct, float* __restrict__ cb)
{
    __shared__ _Float16 sm[64][68];
    const int b = blockIdx.z;
    const int i0 = blockIdx.y * 64;
    const int d0 = blockIdx.x * 64;
    const int t = threadIdx.x;
    const int tx = t & 15, ty = t >> 4;
    const float* wc = w;
    const float* wm = w + 2 * DD;
    const float4 wc4 = *(const float4*)(wc + d0 + tx * 4);
    const float4 wm4 = *(const float4*)(wm + d0 + tx * 4);
    for (int k = 0; k < 4; ++k) {
        const int r = ty + 16 * k;
        const int ig = i0 + r;
        const float4 v = *(const float4*)(ctx + ((size_t)(b * LC + ig)) * DD + d0 + tx * 4);
        f16x4 cmv = { (_Float16)(v.x * wm4.x), (_Float16)(v.y * wm4.y),
                      (_Float16)(v.z * wm4.z), (_Float16)(v.w * wm4.w) };
        *(f16x4*)(cm + ((size_t)(b * LC + ig)) * DD + d0 + tx * 4) = cmv;
        sm[tx * 4 + 0][r] = (_Float16)v.x;
        sm[tx * 4 + 1][r] = (_Float16)v.y;
        sm[tx * 4 + 2][r] = (_Float16)v.z;
        sm[tx * 4 + 3][r] = (_Float16)v.w;
        float p = v.x * wc4.x + v.y * wc4.y + v.z * wc4.z + v.w * wc4.w;
        p += __shfl_xor(p, 1); p += __shfl_xor(p, 2);
        p += __shfl_xor(p, 4); p += __shfl_xor(p, 8);
        if (tx == 0) atomicAdd(&cb[b * LC + ig], p);
    }
    __syncthreads();
    for (int k = 0; k < 4; ++k) {
        const int dd = ty + 16 * k;
        f16x4 o = *(const f16x4*)(&sm[dd][tx * 4]);
        *(f16x4*)(ct + ((size_t)(b * DD + d0 + dd)) * LC + i0 + tx * 4) = o;
    }
}

// Per query row: fp16 copy + qmask = (sum(q) != 0).  qb dropped (exact cancel).
// Also zeros the stats block (cb + lsum) -- runs BEFORE prep_ctx/gemm1.
__global__ __launch_bounds__(128) void prep_q(
    const float* __restrict__ q, _Float16* __restrict__ qh, float* __restrict__ qmask,
    float* __restrict__ stats, int nzero)
{
    const int j = blockIdx.x;
    const int t = threadIdx.x;
    const int g = j * 128 + t;
    if (g < nzero) stats[g] = 0.0f;
    const float4 v = *(const float4*)(q + (size_t)j * DD + t * 4);
    f16x4 qv = { (_Float16)v.x, (_Float16)v.y, (_Float16)v.z, (_Float16)v.w };
    *(f16x4*)(qh + (size_t)j * DD + t * 4) = qv;
    float sq = v.x + v.y + v.z + v.w;
    for (int m = 1; m < 64; m <<= 1) sq += __shfl_xor(sq, m);
    __shared__ float ss[2];
    if ((t & 63) == 0) ss[t >> 6] = sq;
    __syncthreads();
    if (t == 0) qmask[j] = ((ss[0] + ss[1]) != 0.0f) ? 1.0f : 0.0f;
}

// GEMM1: E[b,j,i] = exp( cm[b,i,:].qh[j,:] + cb[b,i] ), fp16 out.
// M-dim = i (A = cm), N-dim = j (B = qh); packed 8B E stores, float4 cb loads.
// lsum[b,j] via LDS reduce + one global atomic per j. Proven round-1 form.
__global__ __launch_bounds__(256) void gemm1(
    const _Float16* __restrict__ qh, const _Float16* __restrict__ cm,
    const float* __restrict__ cb,
    _Float16* __restrict__ E, float* __restrict__ lsum)
{
    __shared__ __align__(16) _Float16 smA[128 * 32];
    __shared__ __align__(16) _Float16 smB[128 * 32];
    int orig = blockIdx.x + 16 * (blockIdx.y + 8 * blockIdx.z);
    int wg = (orig & 7) * (2048 >> 3) + (orig >> 3);
    const int m0 = (wg & 15) * 128;          // i-tile
    const int n0 = ((wg >> 4) & 7) * 128;    // j-tile
    const int b  = wg >> 7;
    const int t = threadIdx.x;
    const int lane = t & 63;
    const int wid = t >> 6;
    const int wvm = wid >> 1, wvn = wid & 1;
    const int li = lane & 15, lg = lane >> 4;
    f32x4 acc[4][4] = {};
    const int srow = lane >> 2;          // 0..15
    const int scol = (lane & 3) * 8;     // f16 elems within row
    const _Float16* gA0 = cm + ((size_t)(b * LC + m0 + wid * 32 + srow)) * DD + scol;
    const _Float16* gA1 = gA0 + (size_t)16 * DD;
    const _Float16* gB0 = qh + (size_t)(n0 + wid * 32 + srow) * DD + scol;
    const _Float16* gB1 = gB0 + (size_t)16 * DD;
    _Float16* sA0 = smA + wid * 32 * 32;
    _Float16* sA1 = sA0 + 16 * 32;
    _Float16* sB0 = smB + wid * 32 * 32;
    _Float16* sB1 = sB0 + 16 * 32;
    for (int ks = 0; ks < DD; ks += 32) {
        __syncthreads();                 // previous iter's ds_reads done
        async16(sA0, gA0 + ks);
        async16(sA1, gA1 + ks);
        async16(sB0, gB0 + ks);
        async16(sB1, gB1 + ks);
        __syncthreads();                 // staged data visible (barrier drains vmcnt)
        f16x8 af[4], bf[4];
        #pragma unroll
        for (int mt = 0; mt < 4; ++mt)
            af[mt] = *(const f16x8*)(smA + (wvm * 64 + mt * 16 + li) * 32 + lg * 8);
        #pragma unroll
        for (int nt = 0; nt < 4; ++nt)
            bf[nt] = *(const f16x8*)(smB + (wvn * 64 + nt * 16 + li) * 32 + lg * 8);
        #pragma unroll
        for (int mt = 0; mt < 4; ++mt)
            #pragma unroll
            for (int nt = 0; nt < 4; ++nt)
                acc[mt][nt] = MFMA16(af[mt], bf[nt], acc[mt][nt], 0, 0, 0);
    }
    __syncthreads();
    float* rs = (float*)smA;
    if (t < 128) rs[t] = 0.0f;
    __syncthreads();
    f32x4 cb4[4];
    #pragma unroll
    for (int mt = 0; mt < 4; ++mt)
        cb4[mt] = *(const f32x4*)(cb + b * LC + m0 + wvm * 64 + mt * 16 + lg * 4);
    #pragma unroll
    for (int nt = 0; nt < 4; ++nt) {
        const int jl = wvn * 64 + nt * 16 + li;
        const int j = n0 + jl;
        _Float16* Ej = E + ((size_t)(b * LQ + j)) * LC + m0 + wvm * 64;
        float rsv = 0.0f;
        #pragma unroll
        for (int mt = 0; mt < 4; ++mt) {
            f16x4 ev;
            #pragma unroll
            for (int r = 0; r < 4; ++r) {
                float e = __expf(acc[mt][nt][r] + cb4[mt][r]);
                rsv += e;
                ev[r] = (_Float16)e;
            }
            *(f16x4*)(Ej + mt * 16 + lg * 4) = ev;   // 4 consecutive i, 8B store
        }
        rsv += __shfl_xor(rsv, 16);
        rsv += __shfl_xor(rsv, 32);
        if (lg == 0) atomicAdd(&rs[jl], rsv);
    }
    __syncthreads();
    if (t < 128) atomicAdd(&lsum[b * LQ + n0 + t], rs[t]);
}

// GEMM2: H[b,j,d] = (qmask[j]/lsum[b,j]) * sum_i E[b,j,i] * ct[b,d,i]
// M-dim = d (A = ct), N-dim = j (B = E); float4 H stores. Proven round-1 form.
__global__ __launch_bounds__(256) void gemm2(
    const _Float16* __restrict__ E, const _Float16* __restrict__ ct,
    const float* __restrict__ lsum, const float* __restrict__ qmask,
    float* __restrict__ H)
{
    __shared__ __align__(16) _Float16 smA[128 * 32];
    __shared__ __align__(16) _Float16 smB[128 * 32];
    int orig = blockIdx.x + 4 * (blockIdx.y + 8 * blockIdx.z);
    int wg = (orig & 7) * (512 >> 3) + (orig >> 3);
    const int m0 = (wg & 3) * 128;           // d-tile
    const int n0 = ((wg >> 2) & 7) * 128;    // j-tile
    const int b  = wg >> 5;
    const int t = threadIdx.x;
    const int lane = t & 63;
    const int wid = t >> 6;
    const int wvm = wid >> 1, wvn = wid & 1;
    const int li = lane & 15, lg = lane >> 4;
    f32x4 acc[4][4] = {};
    const int srow = lane >> 2;
    const int scol = (lane & 3) * 8;
    const _Float16* gA0 = ct + ((size_t)(b * DD + m0 + wid * 32 + srow)) * LC + scol;
    const _Float16* gA1 = gA0 + (size_t)16 * LC;
    const _Float16* gB0 = E + ((size_t)(b * LQ + n0 + wid * 32 + srow)) * LC + scol;
    const _Float16* gB1 = gB0 + (size_t)16 * LC;
    _Float16* sA0 = smA + wid * 32 * 32;
    _Float16* sA1 = sA0 + 16 * 32;
    _Float16* sB0 = smB + wid * 32 * 32;
    _Float16* sB1 = sB0 + 16 * 32;
    for (int ks = 0; ks < LC; ks += 32) {
        __syncthreads();
        async16(sA0, gA0 + ks);
        async16(sA1, gA1 + ks);
        async16(sB0, gB0 + ks);
        async16(sB1, gB1 + ks);
        __syncthreads();
        f16x8 af[4], bf[4];
        #pragma unroll
        for (int mt = 0; mt < 4; ++mt)
            af[mt] = *(const f16x8*)(smA + (wvm * 64 + mt * 16 + li) * 32 + lg * 8);
        #pragma unroll
        for (int nt = 0; nt < 4; ++nt)
            bf[nt] = *(const f16x8*)(smB + (wvn * 64 + nt * 16 + li) * 32 + lg * 8);
        #pragma unroll
        for (int mt = 0; mt < 4; ++mt)
            #pragma unroll
            for (int nt = 0; nt < 4; ++nt)
                acc[mt][nt] = MFMA16(af[mt], bf[nt], acc[mt][nt], 0, 0, 0);
    }
    #pragma unroll
    for (int nt = 0; nt < 4; ++nt) {
        const int j = n0 + wvn * 64 + nt * 16 + li;
        const float s = qmask[j] / lsum[b * LQ + j];
        float* Hj = H + ((size_t)(b * LQ + j)) * DD + m0 + wvm * 64;
        #pragma unroll
        for (int mt = 0; mt < 4; ++mt) {
            f32x4 o = acc[mt][nt] * s;
            *(f32x4*)(Hj + mt * 16 + lg * 4) = o;    // 4 consecutive d, 16B store
        }
    }
}

// Fused colsum + G-write. Block owns (b, 128-i chunk):
//   phase 1: cs[i] = sum_j (qmask[j]/lsum[b,j]) * E[b,j,i]  (LDS-resident, atomic-free)
//   phase 2: G[b,i,0:512] = ctx;  G[b,i,512:1024] = ctx * cs[i]
__global__ __launch_bounds__(256) void colsum_gw(
    const _Float16* __restrict__ E, const float* __restrict__ lsum,
    const float* __restrict__ qmask, const float* __restrict__ ctx,
    float* __restrict__ G)
{
    __shared__ float sscale[LQ];
    __shared__ float red[16][132];   // +4 pad: spreads jg across banks
    __shared__ float csh[128];
    const int b = blockIdx.y;
    const int i0 = blockIdx.x * 128;
    const int t = threadIdx.x;
    for (int j = t; j < LQ; j += 256) sscale[j] = qmask[j] / lsum[b * LQ + j];
    __syncthreads();
    const int iw = t & 15;           // 16 x 8 = 128 i per block
    const int jg = t >> 4;           // 16 j-groups of 64
    const _Float16* Eb = E + ((size_t)(b * LQ + jg * 64)) * LC + i0 + iw * 8;
    float acc[8] = {};
    #pragma unroll 4
    for (int k = 0; k < 64; ++k) {
        f16x8 v = *(const f16x8*)(Eb + (size_t)k * LC);
        const float s = sscale[jg * 64 + k];
        #pragma unroll
        for (int q = 0; q < 8; ++q) acc[q] += s * (float)v[q];
    }
    #pragma unroll
    for (int q = 0; q < 8; ++q) red[jg][iw * 8 + q] = acc[q];
    __syncthreads();
    if (t < 128) {
        float s = 0.0f;
        #pragma unroll
        for (int g = 0; g < 16; ++g) s += red[g][t];
        csh[t] = s;
    }
    __syncthreads();
    // phase 2: 128 rows x 512 d; thread covers d-chunk (t&127)*4, rows t>>7, +2
    const int dcol = (t & 127) * 4;
    #pragma unroll 4
    for (int r = t >> 7; r < 128; r += 2) {
        const size_t ro = (size_t)(b * LC + i0 + r);
        const float c = csh[r];
        const float4 v = *(const float4*)(ctx + ro * DD + dcol);
        *(float4*)(G + ro * (2 * DD) + dcol) = v;
        float4 u; u.x = v.x * c; u.y = v.y * c; u.z = v.z * c; u.w = v.w * c;
        *(float4*)(G + ro * (2 * DD) + DD + dcol) = u;
    }
}

extern "C" void kernel_launch(void* const* d_in, const int* in_sizes, int n_in,
                              void* d_out, int out_size, void* d_ws, size_t ws_size,
                              hipStream_t stream)
{
    (void)in_sizes; (void)n_in; (void)out_size; (void)ws_size;
    const float* ctx = (const float*)d_in[0];
    const float* qry = (const float*)d_in[1];
    const float* w   = (const float*)d_in[2];
    float* G = (float*)d_out;
    float* H = G + (size_t)BB * LC * (2 * DD);

    char* ws = (char*)d_ws;
    _Float16* E  = (_Float16*)ws;                            // 64 MB
    _Float16* cm = (_Float16*)(ws + ((size_t)64 << 20));     // 32 MB
    _Float16* ct = (_Float16*)(ws + ((size_t)96 << 20));     // 32 MB
    _Float16* qh = (_Float16*)(ws + ((size_t)128 << 20));    // 1 MB
    float* stats = (float*)(ws + ((size_t)130 << 20));
    float* cb    = stats;              // BB*LC
    float* lsum  = cb + BB * LC;       // BB*LQ
    float* qmask = lsum + BB * LQ;     // LQ

    const int nzero = BB * LC + BB * LQ;   // cb + lsum
    // prep_q first: zeros cb+lsum (before prep_ctx's cb atomics / gemm1's lsum atomics)
    prep_q<<<dim3(LQ), 128, 0, stream>>>(qry, qh, qmask, stats, nzero);
    prep_ctx<<<dim3(DD / 64, LC / 64, BB), 256, 0, stream>>>(ctx, w, cm, ct, cb);
    gemm1<<<dim3(LC / 128, LQ / 128, BB), 256, 0, stream>>>(qh, cm, cb, E, lsum);
    gemm2<<<dim3(DD / 128, LQ / 128, BB), 256, 0, stream>>>(E, ct, lsum, qmask, H);
    colsum_gw<<<dim3(LC / 128, BB), 256, 0, stream>>>(E, lsum, qmask, ctx, G);
}

// Round 4
// 345.160 us; speedup vs baseline: 1.0880x; 1.0880x over previous
//
#include <hip/hip_runtime.h>
#include <stdint.h>

#define BB 16
#define LC 2048
#define LQ 1024
#define DD 512

typedef _Float16 f16x8 __attribute__((ext_vector_type(8)));
typedef _Float16 f16x4 __attribute__((ext_vector_type(4)));
typedef float f32x4 __attribute__((ext_vector_type(4)));

#define MFMA16 __builtin_amdgcn_mfma_f32_16x16x32_f16

// Async global->LDS, 16B per lane. LDS dest = wave-uniform base + lane*16.
__device__ __forceinline__ void async16(_Float16* lds, const _Float16* g) {
    __builtin_amdgcn_global_load_lds(
        (const __attribute__((address_space(1))) void*)g,
        (__attribute__((address_space(3))) void*)lds, 16, 0, 0);
}

// Per 64x64 tile of context: write cm = ctx*wm (i,d)-major fp16,
// ct = ctx^T (d,i)-major fp16 (via LDS transpose), and accumulate cb = ctx.wc
__global__ __launch_bounds__(256) void prep_ctx(
    const float* __restrict__ ctx, const float* __restrict__ w,
    _Float16* __restrict__ cm, _Float16* __restrict__ ct, float* __restrict__ cb)
{
    __shared__ _Float16 sm[64][68];
    const int b = blockIdx.z;
    const int i0 = blockIdx.y * 64;
    const int d0 = blockIdx.x * 64;
    const int t = threadIdx.x;
    const int tx = t & 15, ty = t >> 4;
    const float* wc = w;
    const float* wm = w + 2 * DD;
    const float4 wc4 = *(const float4*)(wc + d0 + tx * 4);
    const float4 wm4 = *(const float4*)(wm + d0 + tx * 4);
    for (int k = 0; k < 4; ++k) {
        const int r = ty + 16 * k;
        const int ig = i0 + r;
        const float4 v = *(const float4*)(ctx + ((size_t)(b * LC + ig)) * DD + d0 + tx * 4);
        f16x4 cmv = { (_Float16)(v.x * wm4.x), (_Float16)(v.y * wm4.y),
                      (_Float16)(v.z * wm4.z), (_Float16)(v.w * wm4.w) };
        *(f16x4*)(cm + ((size_t)(b * LC + ig)) * DD + d0 + tx * 4) = cmv;
        sm[tx * 4 + 0][r] = (_Float16)v.x;
        sm[tx * 4 + 1][r] = (_Float16)v.y;
        sm[tx * 4 + 2][r] = (_Float16)v.z;
        sm[tx * 4 + 3][r] = (_Float16)v.w;
        float p = v.x * wc4.x + v.y * wc4.y + v.z * wc4.z + v.w * wc4.w;
        p += __shfl_xor(p, 1); p += __shfl_xor(p, 2);
        p += __shfl_xor(p, 4); p += __shfl_xor(p, 8);
        if (tx == 0) atomicAdd(&cb[b * LC + ig], p);
    }
    __syncthreads();
    for (int k = 0; k < 4; ++k) {
        const int dd = ty + 16 * k;
        f16x4 o = *(const f16x4*)(&sm[dd][tx * 4]);
        *(f16x4*)(ct + ((size_t)(b * DD + d0 + dd)) * LC + i0 + tx * 4) = o;
    }
}

// Per query row: fp16 copy + qmask = (sum(q) != 0).  qb dropped (exact cancel).
// Also zeros the stats block (cb + lsum) -- runs BEFORE prep_ctx/gemm1.
__global__ __launch_bounds__(128) void prep_q(
    const float* __restrict__ q, _Float16* __restrict__ qh, float* __restrict__ qmask,
    float* __restrict__ stats, int nzero)
{
    const int j = blockIdx.x;
    const int t = threadIdx.x;
    const int g = j * 128 + t;
    if (g < nzero) stats[g] = 0.0f;
    const float4 v = *(const float4*)(q + (size_t)j * DD + t * 4);
    f16x4 qv = { (_Float16)v.x, (_Float16)v.y, (_Float16)v.z, (_Float16)v.w };
    *(f16x4*)(qh + (size_t)j * DD + t * 4) = qv;
    float sq = v.x + v.y + v.z + v.w;
    for (int m = 1; m < 64; m <<= 1) sq += __shfl_xor(sq, m);
    __shared__ float ss[2];
    if ((t & 63) == 0) ss[t >> 6] = sq;
    __syncthreads();
    if (t == 0) qmask[j] = ((ss[0] + ss[1]) != 0.0f) ? 1.0f : 0.0f;
}

// GEMM1: E[b,j,i] = exp( cm[b,i,:].qh[j,:] + cb[b,i] ), fp16 out.
// M-dim = i (A = cm), N-dim = j (B = qh); packed 8B E stores, float4 cb loads.
// lsum[b,j] via LDS reduce + one global atomic per j. Proven round-1 form.
__global__ __launch_bounds__(256) void gemm1(
    const _Float16* __restrict__ qh, const _Float16* __restrict__ cm,
    const float* __restrict__ cb,
    _Float16* __restrict__ E, float* __restrict__ lsum)
{
    __shared__ __align__(16) _Float16 smA[128 * 32];
    __shared__ __align__(16) _Float16 smB[128 * 32];
    int orig = blockIdx.x + 16 * (blockIdx.y + 8 * blockIdx.z);
    int wg = (orig & 7) * (2048 >> 3) + (orig >> 3);
    const int m0 = (wg & 15) * 128;          // i-tile
    const int n0 = ((wg >> 4) & 7) * 128;    // j-tile
    const int b  = wg >> 7;
    const int t = threadIdx.x;
    const int lane = t & 63;
    const int wid = t >> 6;
    const int wvm = wid >> 1, wvn = wid & 1;
    const int li = lane & 15, lg = lane >> 4;
    f32x4 acc[4][4] = {};
    const int srow = lane >> 2;          // 0..15
    const int scol = (lane & 3) * 8;     // f16 elems within row
    const _Float16* gA0 = cm + ((size_t)(b * LC + m0 + wid * 32 + srow)) * DD + scol;
    const _Float16* gA1 = gA0 + (size_t)16 * DD;
    const _Float16* gB0 = qh + (size_t)(n0 + wid * 32 + srow) * DD + scol;
    const _Float16* gB1 = gB0 + (size_t)16 * DD;
    _Float16* sA0 = smA + wid * 32 * 32;
    _Float16* sA1 = sA0 + 16 * 32;
    _Float16* sB0 = smB + wid * 32 * 32;
    _Float16* sB1 = sB0 + 16 * 32;
    for (int ks = 0; ks < DD; ks += 32) {
        __syncthreads();                 // previous iter's ds_reads done
        async16(sA0, gA0 + ks);
        async16(sA1, gA1 + ks);
        async16(sB0, gB0 + ks);
        async16(sB1, gB1 + ks);
        __syncthreads();                 // staged data visible (barrier drains vmcnt)
        f16x8 af[4], bf[4];
        #pragma unroll
        for (int mt = 0; mt < 4; ++mt)
            af[mt] = *(const f16x8*)(smA + (wvm * 64 + mt * 16 + li) * 32 + lg * 8);
        #pragma unroll
        for (int nt = 0; nt < 4; ++nt)
            bf[nt] = *(const f16x8*)(smB + (wvn * 64 + nt * 16 + li) * 32 + lg * 8);
        #pragma unroll
        for (int mt = 0; mt < 4; ++mt)
            #pragma unroll
            for (int nt = 0; nt < 4; ++nt)
                acc[mt][nt] = MFMA16(af[mt], bf[nt], acc[mt][nt], 0, 0, 0);
    }
    __syncthreads();
    float* rs = (float*)smA;
    if (t < 128) rs[t] = 0.0f;
    __syncthreads();
    f32x4 cb4[4];
    #pragma unroll
    for (int mt = 0; mt < 4; ++mt)
        cb4[mt] = *(const f32x4*)(cb + b * LC + m0 + wvm * 64 + mt * 16 + lg * 4);
    #pragma unroll
    for (int nt = 0; nt < 4; ++nt) {
        const int jl = wvn * 64 + nt * 16 + li;
        const int j = n0 + jl;
        _Float16* Ej = E + ((size_t)(b * LQ + j)) * LC + m0 + wvm * 64;
        float rsv = 0.0f;
        #pragma unroll
        for (int mt = 0; mt < 4; ++mt) {
            f16x4 ev;
            #pragma unroll
            for (int r = 0; r < 4; ++r) {
                float e = __expf(acc[mt][nt][r] + cb4[mt][r]);
                rsv += e;
                ev[r] = (_Float16)e;
            }
            *(f16x4*)(Ej + mt * 16 + lg * 4) = ev;   // 4 consecutive i, 8B store
        }
        rsv += __shfl_xor(rsv, 16);
        rsv += __shfl_xor(rsv, 32);
        if (lg == 0) atomicAdd(&rs[jl], rsv);
    }
    __syncthreads();
    if (t < 128) atomicAdd(&lsum[b * LQ + n0 + t], rs[t]);
}

// Fused dispatch: blocks 0..511 run GEMM2, blocks 512..767 run colsum.
// Both depend only on gemm1's outputs (E, lsum) -- no intra-dispatch deps.
// gemm2 (compute-bound) and colsum (BW-bound) co-resident: colsum's 64MB
// E-read hides under gemm2's MFMA instead of running as a serial tail.
__global__ __launch_bounds__(256) void gemm2_colsum(
    const _Float16* __restrict__ E, const _Float16* __restrict__ ct,
    const float* __restrict__ lsum, const float* __restrict__ qmask,
    float* __restrict__ H, float* __restrict__ cs)
{
    __shared__ __align__(16) char shm[16384];
    const int t = threadIdx.x;
    if (blockIdx.x < 512) {
        // ---- GEMM2 role: H[b,j,d] = (qmask[j]/lsum[b,j]) * sum_i E[b,j,i]*ct[b,d,i]
        _Float16* smA = (_Float16*)shm;             // 128x32 = 8KB
        _Float16* smB = smA + 128 * 32;             // 128x32 = 8KB
        const int orig = blockIdx.x;
        const int wg = (orig & 7) * 64 + (orig >> 3);   // bijective: 512 % 8 == 0
        const int m0 = (wg & 3) * 128;           // d-tile
        const int n0 = ((wg >> 2) & 7) * 128;    // j-tile
        const int b  = wg >> 5;
        const int lane = t & 63;
        const int wid = t >> 6;
        const int wvm = wid >> 1, wvn = wid & 1;
        const int li = lane & 15, lg = lane >> 4;
        f32x4 acc[4][4] = {};
        const int srow = lane >> 2;
        const int scol = (lane & 3) * 8;
        const _Float16* gA0 = ct + ((size_t)(b * DD + m0 + wid * 32 + srow)) * LC + scol;
        const _Float16* gA1 = gA0 + (size_t)16 * LC;
        const _Float16* gB0 = E + ((size_t)(b * LQ + n0 + wid * 32 + srow)) * LC + scol;
        const _Float16* gB1 = gB0 + (size_t)16 * LC;
        _Float16* sA0 = smA + wid * 32 * 32;
        _Float16* sA1 = sA0 + 16 * 32;
        _Float16* sB0 = smB + wid * 32 * 32;
        _Float16* sB1 = sB0 + 16 * 32;
        for (int ks = 0; ks < LC; ks += 32) {
            __syncthreads();
            async16(sA0, gA0 + ks);
            async16(sA1, gA1 + ks);
            async16(sB0, gB0 + ks);
            async16(sB1, gB1 + ks);
            __syncthreads();
            f16x8 af[4], bf[4];
            #pragma unroll
            for (int mt = 0; mt < 4; ++mt)
                af[mt] = *(const f16x8*)(smA + (wvm * 64 + mt * 16 + li) * 32 + lg * 8);
            #pragma unroll
            for (int nt = 0; nt < 4; ++nt)
                bf[nt] = *(const f16x8*)(smB + (wvn * 64 + nt * 16 + li) * 32 + lg * 8);
            #pragma unroll
            for (int mt = 0; mt < 4; ++mt)
                #pragma unroll
                for (int nt = 0; nt < 4; ++nt)
                    acc[mt][nt] = MFMA16(af[mt], bf[nt], acc[mt][nt], 0, 0, 0);
        }
        #pragma unroll
        for (int nt = 0; nt < 4; ++nt) {
            const int j = n0 + wvn * 64 + nt * 16 + li;
            const float s = qmask[j] / lsum[b * LQ + j];
            float* Hj = H + ((size_t)(b * LQ + j)) * DD + m0 + wvm * 64;
            #pragma unroll
            for (int mt = 0; mt < 4; ++mt) {
                f32x4 o = acc[mt][nt] * s;
                *(f32x4*)(Hj + mt * 16 + lg * 4) = o;    // 4 consecutive d, 16B store
            }
        }
    } else {
        // ---- colsum role: cs[b,i] = sum_j (qmask[j]/lsum[b,j]) * E[b,j,i]
        float* sscale = (float*)shm;                       // 4KB
        float (*red)[132] = (float(*)[132])(shm + 4096);   // 16x132x4 = 8.25KB
        const int orig2 = blockIdx.x - 512;                // 0..255
        const int b = orig2 >> 4;
        const int i0 = (orig2 & 15) * 128;
        for (int j = t; j < LQ; j += 256) sscale[j] = qmask[j] / lsum[b * LQ + j];
        __syncthreads();
        const int iw = t & 15;           // 16 x 8 = 128 i per block
        const int jg = t >> 4;           // 16 j-groups of 64
        const _Float16* Eb = E + ((size_t)(b * LQ + jg * 64)) * LC + i0 + iw * 8;
        float acc[8] = {};
        #pragma unroll 4
        for (int k = 0; k < 64; ++k) {
            f16x8 v = *(const f16x8*)(Eb + (size_t)k * LC);
            const float s = sscale[jg * 64 + k];
            #pragma unroll
            for (int q = 0; q < 8; ++q) acc[q] += s * (float)v[q];
        }
        #pragma unroll
        for (int q = 0; q < 8; ++q) red[jg][iw * 8 + q] = acc[q];
        __syncthreads();
        if (t < 128) {
            float s = 0.0f;
            #pragma unroll
            for (int g = 0; g < 16; ++g) s += red[g][t];
            cs[b * LC + i0 + t] = s;
        }
    }
}

// G[b,i,0:512] = ctx; G[b,i,512:1024] = ctx * colsum
__global__ __launch_bounds__(128) void gwrite(
    const float* __restrict__ ctx, const float* __restrict__ cs, float* __restrict__ G)
{
    const int b = blockIdx.y, i = blockIdx.x, t = threadIdx.x;
    const float c = cs[b * LC + i];
    const size_t ro = (size_t)(b * LC + i);
    const float4 v = *(const float4*)(ctx + ro * DD + t * 4);
    float4 u; u.x = v.x * c; u.y = v.y * c; u.z = v.z * c; u.w = v.w * c;
    *(float4*)(G + ro * (2 * DD) + t * 4) = v;
    *(float4*)(G + ro * (2 * DD) + DD + t * 4) = u;
}

extern "C" void kernel_launch(void* const* d_in, const int* in_sizes, int n_in,
                              void* d_out, int out_size, void* d_ws, size_t ws_size,
                              hipStream_t stream)
{
    (void)in_sizes; (void)n_in; (void)out_size; (void)ws_size;
    const float* ctx = (const float*)d_in[0];
    const float* qry = (const float*)d_in[1];
    const float* w   = (const float*)d_in[2];
    float* G = (float*)d_out;
    float* H = G + (size_t)BB * LC * (2 * DD);

    char* ws = (char*)d_ws;
    _Float16* E  = (_Float16*)ws;                            // 64 MB
    _Float16* cm = (_Float16*)(ws + ((size_t)64 << 20));     // 32 MB
    _Float16* ct = (_Float16*)(ws + ((size_t)96 << 20));     // 32 MB
    _Float16* qh = (_Float16*)(ws + ((size_t)128 << 20));    // 1 MB
    float* stats = (float*)(ws + ((size_t)130 << 20));
    float* cb    = stats;              // BB*LC
    float* lsum  = cb + BB * LC;       // BB*LQ
    float* cs    = lsum + BB * LQ;     // BB*LC (direct store, no zero needed)
    float* qmask = cs + BB * LC;       // LQ

    const int nzero = BB * LC + BB * LQ;   // cb + lsum
    // prep_q first: zeros cb+lsum (before prep_ctx's cb atomics / gemm1's lsum atomics)
    prep_q<<<dim3(LQ), 128, 0, stream>>>(qry, qh, qmask, stats, nzero);
    prep_ctx<<<dim3(DD / 64, LC / 64, BB), 256, 0, stream>>>(ctx, w, cm, ct, cb);
    gemm1<<<dim3(LC / 128, LQ / 128, BB), 256, 0, stream>>>(qh, cm, cb, E, lsum);
    gemm2_colsum<<<dim3(512 + 256), 256, 0, stream>>>(E, ct, lsum, qmask, H, cs);
    gwrite<<<dim3(LC, BB), 128, 0, stream>>>(ctx, cs, G);
}